// Round 2
// baseline (184.278 us; speedup 1.0000x reference)
//
#include <hip/hip_runtime.h>

#define T_DIM 2048
#define F_DIM 128
#define B_DIM 16
#define NS 10
#define TPB 256
#define EPT 8   // elements (t's) per thread = T_DIM / TPB

// Collision-free fast-math wrappers (avoid __exp2f/__log2f glibc macro clash).
__device__ __forceinline__ float fast_exp2(float x) { return __builtin_amdgcn_exp2f(x); }
__device__ __forceinline__ float fast_log2(float x) { return __builtin_amdgcn_logf(x); }

__global__ __launch_bounds__(TPB) void pcen_kernel(
    const float* __restrict__ x,
    const float* __restrict__ s_log,
    const float* __restrict__ alpha_log,
    const float* __restrict__ delta_log,
    const float* __restrict__ r_log,
    float* __restrict__ out)
{
    const int bf   = blockIdx.x;         // b*F + f
    const int b    = bf / F_DIM;
    const int f    = bf % F_DIM;
    const int tid  = threadIdx.x;
    const int lane = tid & 63;
    const int wave = tid >> 6;

    const float* xrow = x + (size_t)bf * T_DIM;

    // Load this thread's 8 contiguous x values (coalesced float4 x2).
    float xv[EPT];
    {
        const float4* xr4 = (const float4*)(xrow + tid * EPT);
        float4 p0 = xr4[0];
        float4 p1 = xr4[1];
        xv[0] = p0.x; xv[1] = p0.y; xv[2] = p0.z; xv[3] = p0.w;
        xv[4] = p1.x; xv[5] = p1.y; xv[6] = p1.z; xv[7] = p1.w;
    }

    // Block carry-in: with uniform recurrence y = a*y_prev + s*x,
    // carry-in = x0 reproduces y_0 = x_0 exactly ((1-s)x0 + s*x0 = x0).
    const float x0 = xrow[0];

    // Per-f parameters (cheap scalar setup; expf goes through ocml, fine).
    const float alpha   = expf(alpha_log[f]);
    const float delta   = expf(delta_log[f]);
    const float r       = expf(r_log[f]);
    const float delta_r = fast_exp2(r * fast_log2(delta));   // delta^r
    const float neg_alpha = -alpha;

    __shared__ float lds_m[4];
    __shared__ float lds_v[4];

    float* orow = out + (size_t)(b * NS) * (F_DIM * (size_t)T_DIM)
                      + (size_t)f * T_DIM + (size_t)tid * EPT;

    for (int si = 0; si < NS; ++si) {
        const float s = expf(s_log[si]);
        const float a = 1.0f - s;

        // Local inclusive scan with zero carry-in; keep only the last value.
        float c = 0.0f;
        #pragma unroll
        for (int i = 0; i < EPT; ++i) c = fmaf(a, c, s * xv[i]);
        const float a2 = a * a, a4 = a2 * a2, A8 = a4 * a4;  // a^EPT

        // Wave-level inclusive scan of affine functions (m, v): f(c) = m*c + v.
        float m = A8, v = c;
        #pragma unroll
        for (int d = 1; d < 64; d <<= 1) {
            float m_up = __shfl_up(m, d);
            float v_up = __shfl_up(v, d);
            if (lane >= d) { v = fmaf(m, v_up, v); m *= m_up; }
        }
        // Exclusive-within-wave pair from inclusive via shfl_up(1).
        float m_e = __shfl_up(m, 1);
        float v_e = __shfl_up(v, 1);
        if (lane == 0) { m_e = 1.0f; v_e = 0.0f; }

        if (si) __syncthreads();          // protect LDS reuse across s iterations
        if (lane == 63) { lds_m[wave] = m; lds_v[wave] = v; }
        __syncthreads();

        // Carry into this wave: apply composites of preceding waves to x0.
        float cw = x0;
        for (int w = 0; w < wave; ++w) cw = fmaf(lds_m[w], cw, lds_v[w]);
        // Carry into this thread.
        const float cin = fmaf(m_e, cw, v_e);

        // Final pass: recompute scan with true carry-in, fuse PCEN pointwise.
        float o[EPT];
        float cc = cin;
        #pragma unroll
        for (int i = 0; i < EPT; ++i) {
            cc = fmaf(a, cc, s * xv[i]);                       // smoother value
            // smooth = (EPS + sm)^(-alpha)
            float smooth = fast_exp2(neg_alpha * fast_log2(cc + 1e-5f));
            float base   = fmaf(xv[i], smooth, delta);         // x*smooth + delta
            o[i] = fast_exp2(r * fast_log2(base)) - delta_r;   // base^r - delta^r
        }

        float4* ow = (float4*)(orow + (size_t)si * (F_DIM * T_DIM));
        ow[0] = make_float4(o[0], o[1], o[2], o[3]);
        ow[1] = make_float4(o[4], o[5], o[6], o[7]);
    }
}

extern "C" void kernel_launch(void* const* d_in, const int* in_sizes, int n_in,
                              void* d_out, int out_size, void* d_ws, size_t ws_size,
                              hipStream_t stream) {
    const float* x         = (const float*)d_in[0];
    const float* s_log     = (const float*)d_in[1];
    const float* alpha_log = (const float*)d_in[2];
    const float* delta_log = (const float*)d_in[3];
    const float* r_log     = (const float*)d_in[4];
    float* out = (float*)d_out;

    pcen_kernel<<<dim3(B_DIM * F_DIM), dim3(TPB), 0, stream>>>(
        x, s_log, alpha_log, delta_log, r_log, out);
}